// Round 11
// baseline (141.429 us; speedup 1.0000x reference)
//
#include <hip/hip_runtime.h>
#include <math.h>

// Problem constants: B=64, L=256, H=64
#define PB 64
#define PL 256
#define PH 64
#define TEMP 0.07f
#define NEG_INF_F (-1e9f)

// Fragment-major layout: per slab (one b or one c), 16 tiles x 1024 elems.
#define KFTILE 1024
#define KFSLAB (16 * KFTILE)   // 16384 elems = 32 KB per slab
#define BGRP   2               // b's per block in the scores kernel
#define NREP   4               // PROBE: repeat colbert's compute 4x inside one dispatch

typedef short short8 __attribute__((ext_vector_type(8)));   // 8 bf16 bit-patterns
typedef float f32x4 __attribute__((ext_vector_type(4)));

__device__ __forceinline__ unsigned short f32_to_bf16(float f) {
    unsigned int u = __float_as_uint(f);
    u += 0x7FFFu + ((u >> 16) & 1u);    // round to nearest even
    return (unsigned short)(u >> 16);
}

// fragment-major element offset for (row p, 16B-chunk cc)
__device__ __forceinline__ int frag_off(int p, int cc) {
    return ((p >> 4) * KFTILE) + ((cc >> 3) * 512) +
           (((((cc >> 1) & 3) * 16) + (p & 15)) * 8) + ((cc & 1) * 4);
}

// ---------------- prep: K AND Q compact/convert into fragment-major ----------------
__global__ __launch_bounds__(256)
void prep_kernel(const float* __restrict__ Q,
                 const float* __restrict__ K,
                 const int*   __restrict__ kmask,
                 const int*   __restrict__ qmask,
                 unsigned short* __restrict__ Qfrag,
                 unsigned short* __restrict__ Kfrag,
                 int* __restrict__ nvK,
                 int* __restrict__ nvQ) {
    const int tid  = threadIdx.x;
    const int lane = tid & 63;
    const int wave = tid >> 6;
    __shared__ int posArr[PL];
    __shared__ int wcnt[4];

    const bool isQ = (blockIdx.x >= 256);
    const int  bid = isQ ? (blockIdx.x - 256) : blockIdx.x;
    const int  idx     = bid >> 2;     // c or b
    const int  quarter = bid & 3;

    const int* mask = isQ ? (qmask + idx * PL) : (kmask + idx * PL);
    const int km = mask[tid];
    unsigned long long bal = __ballot(km != 0);
    int within = __popcll(bal & ((1ull << lane) - 1ull));
    if (lane == 0) wcnt[wave] = __popcll(bal);
    __syncthreads();
    int base = 0;
    #pragma unroll
    for (int w = 0; w < 4; ++w) base += (w < wave) ? wcnt[w] : 0;
    posArr[tid] = km ? (base + within) : -1;
    const int nv = wcnt[0] + wcnt[1] + wcnt[2] + wcnt[3];
    __syncthreads();

    const int sub = lane >> 4;     // row-within-group 0..3
    const int cl  = lane & 15;     // 16B column chunk
    const float* src = (isQ ? Q : K) + (size_t)idx * PL * PH;
    unsigned short* slab = (isQ ? Qfrag : Kfrag) + (size_t)idx * KFSLAB;

    #pragma unroll
    for (int it = 0; it < 4; ++it) {
        int r = quarter * 64 + it * 16 + wave * 4 + sub;
        int p = posArr[r];
        if (p >= 0) {
            float4 v = *(const float4*)(src + (size_t)r * PH + cl * 4);
            ushort4 o;
            o.x = f32_to_bf16(v.x); o.y = f32_to_bf16(v.y);
            o.z = f32_to_bf16(v.z); o.w = f32_to_bf16(v.w);
            *(ushort4*)(slab + frag_off(p, cl)) = o;
        }
    }

    if (!isQ) {
        const int rows16 = (nv + 15) & ~15;
        const int padChunks = (rows16 - nv) * 16;
        if (tid < padChunks) {
            int row = nv + (tid >> 4);
            if (row >= quarter * 64 && row < quarter * 64 + 64)
                *(ushort4*)(slab + frag_off(row, tid & 15)) = (ushort4){0, 0, 0, 0};
        }
        if (quarter == 0 && tid == 0) nvK[idx] = nv;
    } else {
        #pragma unroll
        for (int it = 0; it < 4; ++it) {
            int id2 = it * 256 + tid;
            int row = quarter * 64 + (id2 >> 4);
            if (row >= nv)
                *(ushort4*)(slab + frag_off(row, id2 & 15)) = (ushort4){0, 0, 0, 0};
        }
        if (quarter == 0 && tid == 0) nvQ[idx] = nv;
    }
}

// ---------------- main scores kernel (R8 structure) with NREP probe loop ----------------
// PROBE: the entire compute (including all fragment loads) runs NREP times.
// asm "+v" on the base pointers each rep prevents load hoisting/CSE across reps,
// so rep 1 measures the cold-cache pass and reps 2..4 the warm passes.
__global__ __launch_bounds__(256, 2)
void colbert_scores_mfma(const unsigned short* __restrict__ Qfrag,
                         const unsigned short* __restrict__ Kfrag,
                         const int*   __restrict__ nvK,
                         const int*   __restrict__ nvQ,
                         float*       __restrict__ scores) {
    const int c  = blockIdx.x;
    const int bg = blockIdx.y;
    const int tid  = threadIdx.x;
    const int wave = tid >> 6;
    const int lane = tid & 63;
    const int n    = lane & 15;        // col / row-within-tile index

    __shared__ float red[BGRP][4];

    const int nv       = nvK[c];
    const int ntFull   = nv >> 4;
    const int tailCols = nv & 15;

    const int b0  = bg * BGRP;
    const int nq0 = nvQ[b0];
    const int nq1 = nvQ[b0 + 1];
    const int ntQP = ((nq0 > nq1 ? nq0 : nq1) + 31) >> 5;   // q-tile-pairs (32 rows)

    const f32x4 ZERO4 = (f32x4){0.f, 0.f, 0.f, 0.f};
    const float biasv = (n < tailCols) ? 0.0f : NEG_INF_F;
    const f32x4 BIAS4 = (f32x4){biasv, biasv, biasv, biasv};

    const unsigned short* Qf = Qfrag;
    const unsigned short* Kf = Kfrag;

    #pragma unroll 1
    for (int rep = 0; rep < NREP; ++rep) {
        // opaque pointers: forces genuine re-loads each rep (anti-hoist/CSE)
        asm volatile("" : "+v"(Qf), "+v"(Kf));

        const unsigned short* kb = Kf + (size_t)c * KFSLAB + lane * 8;
        float partial[BGRP] = {0.0f, 0.0f};

        for (int qp = wave; qp < ntQP; qp += 4) {
            short8 aA[BGRP][2][2];
            #pragma unroll
            for (int bi = 0; bi < BGRP; ++bi) {
                const unsigned short* qbase = Qf + (size_t)(b0 + bi) * KFSLAB
                                             + qp * 2 * KFTILE + lane * 8;
                aA[bi][0][0] = *(const short8*)(qbase);
                aA[bi][0][1] = *(const short8*)(qbase + 512);
                aA[bi][1][0] = *(const short8*)(qbase + 1024);
                aA[bi][1][1] = *(const short8*)(qbase + 1536);
            }

            float maxv[BGRP][2][4];
            #pragma unroll
            for (int bi = 0; bi < BGRP; ++bi)
                #pragma unroll
                for (int t = 0; t < 2; ++t)
                    #pragma unroll
                    for (int r = 0; r < 4; ++r) maxv[bi][t][r] = NEG_INF_F;

            int ct = 0;
            for (; ct + 1 < ntFull; ct += 2) {
                const unsigned short* ka = kb + ct * KFTILE;
                short8 kA0 = *(const short8*)(ka);
                short8 kA1 = *(const short8*)(ka + 512);
                short8 kB0 = *(const short8*)(ka + 1024);
                short8 kB1 = *(const short8*)(ka + 1536);

                #pragma unroll
                for (int bi = 0; bi < BGRP; ++bi)
                    #pragma unroll
                    for (int t = 0; t < 2; ++t) {
                        f32x4 accA = __builtin_amdgcn_mfma_f32_16x16x32_bf16(aA[bi][t][0], kA0, ZERO4, 0, 0, 0);
                        accA = __builtin_amdgcn_mfma_f32_16x16x32_bf16(aA[bi][t][1], kA1, accA, 0, 0, 0);
                        f32x4 accB = __builtin_amdgcn_mfma_f32_16x16x32_bf16(aA[bi][t][0], kB0, ZERO4, 0, 0, 0);
                        accB = __builtin_amdgcn_mfma_f32_16x16x32_bf16(aA[bi][t][1], kB1, accB, 0, 0, 0);
                        #pragma unroll
                        for (int r = 0; r < 4; ++r)
                            maxv[bi][t][r] = fmaxf(maxv[bi][t][r], fmaxf(accA[r], accB[r]));
                    }
            }

            if (ntFull & 1) {
                const unsigned short* ka = kb + ct * KFTILE;
                short8 k0 = *(const short8*)(ka);
                short8 k1 = *(const short8*)(ka + 512);
                #pragma unroll
                for (int bi = 0; bi < BGRP; ++bi)
                    #pragma unroll
                    for (int t = 0; t < 2; ++t) {
                        f32x4 acc = __builtin_amdgcn_mfma_f32_16x16x32_bf16(aA[bi][t][0], k0, ZERO4, 0, 0, 0);
                        acc = __builtin_amdgcn_mfma_f32_16x16x32_bf16(aA[bi][t][1], k1, acc, 0, 0, 0);
                        #pragma unroll
                        for (int r = 0; r < 4; ++r)
                            maxv[bi][t][r] = fmaxf(maxv[bi][t][r], acc[r]);
                    }
                ct++;
            }

            if (tailCols) {
                const unsigned short* ka = kb + ct * KFTILE;
                short8 k0 = *(const short8*)(ka);
                short8 k1 = *(const short8*)(ka + 512);
                #pragma unroll
                for (int bi = 0; bi < BGRP; ++bi)
                    #pragma unroll
                    for (int t = 0; t < 2; ++t) {
                        f32x4 acc = __builtin_amdgcn_mfma_f32_16x16x32_bf16(aA[bi][t][0], k0, BIAS4, 0, 0, 0);
                        acc = __builtin_amdgcn_mfma_f32_16x16x32_bf16(aA[bi][t][1], k1, acc, 0, 0, 0);
                        #pragma unroll
                        for (int r = 0; r < 4; ++r)
                            maxv[bi][t][r] = fmaxf(maxv[bi][t][r], acc[r]);
                    }
            }

            #pragma unroll
            for (int bi = 0; bi < BGRP; ++bi)
                #pragma unroll
                for (int t = 0; t < 2; ++t)
                    #pragma unroll
                    for (int r = 0; r < 4; ++r) {
                        float mv = maxv[bi][t][r];
                        mv = fmaxf(mv, __shfl_xor(mv, 1, 16));
                        mv = fmaxf(mv, __shfl_xor(mv, 2, 16));
                        mv = fmaxf(mv, __shfl_xor(mv, 4, 16));
                        mv = fmaxf(mv, __shfl_xor(mv, 8, 16));
                        if (n == 0) partial[bi] += mv;
                    }
        }

        #pragma unroll
        for (int bi = 0; bi < BGRP; ++bi) {
            float p = partial[bi];
            p += __shfl_xor(p, 16, 64);
            p += __shfl_xor(p, 32, 64);
            if (lane == 0) red[bi][wave] = p;
        }

        __syncthreads();
        if (tid < BGRP) {
            float total = red[tid][0] + red[tid][1] + red[tid][2] + red[tid][3];
            scores[(b0 + tid) * PB + c] = total * (1.0f / TEMP);
        }
        __syncthreads();   // red[] reusable next rep
    }
}

// ---------------- finalize: log-softmax CE ----------------
__global__ void finalize_kernel(const float* __restrict__ scores,
                                const int*   __restrict__ labels,
                                float*       __restrict__ out) {
    const int r = threadIdx.x;   // 64 threads, one per row
    const float* row = scores + r * PB;
    float mx = NEG_INF_F;
    for (int j = 0; j < PB; ++j) mx = fmaxf(mx, row[j]);
    float se = 0.0f;
    for (int j = 0; j < PB; ++j) se += expf(row[j] - mx);
    float logp_diag = row[r] - mx - logf(se);
    float w = (float)labels[r];
    float wd = w * logp_diag;
    #pragma unroll
    for (int off = 32; off >= 1; off >>= 1) {
        wd += __shfl_xor(wd, off, 64);
        w  += __shfl_xor(w,  off, 64);
    }
    if (r == 0) out[0] = -wd / fmaxf(w, 1.0f);
}

extern "C" void kernel_launch(void* const* d_in, const int* in_sizes, int n_in,
                              void* d_out, int out_size, void* d_ws, size_t ws_size,
                              hipStream_t stream) {
    const float* Q      = (const float*)d_in[0];
    const float* K      = (const float*)d_in[1];
    const int*   labels = (const int*)d_in[2];
    const int*   qmask  = (const int*)d_in[3];
    const int*   kmask  = (const int*)d_in[4];
    float*       out    = (float*)d_out;

    // ws layout: [scores 16KB][Qfrag 2MB][Kfrag 2MB][nvK 256B][nvQ 256B]
    char* ws = (char*)d_ws;
    float*          scores = (float*)ws;
    unsigned short* Qfrag  = (unsigned short*)(ws + 16 * 1024);
    unsigned short* Kfrag  = (unsigned short*)(ws + 16 * 1024 + 2 * 1024 * 1024);
    int*            nvK    = (int*)(ws + 16 * 1024 + 4 * 1024 * 1024);
    int*            nvQ    = nvK + 64;

    prep_kernel<<<512, 256, 0, stream>>>(Q, K, kmask, qmask, Qfrag, Kfrag, nvK, nvQ);

    dim3 grid(PB, PB / BGRP);
    colbert_scores_mfma<<<grid, 256, 0, stream>>>(Qfrag, Kfrag, nvK, nvQ, scores);
    finalize_kernel<<<1, 64, 0, stream>>>(scores, labels, out);
}

// Round 12
// 97.581 us; speedup vs baseline: 1.4494x; 1.4494x over previous
//
#include <hip/hip_runtime.h>
#include <math.h>

// Problem constants: B=64, L=256, H=64
#define PB 64
#define PL 256
#define PH 64
#define TEMP 0.07f
#define NEG_INF_F (-1e9f)

// Fragment-major layout: per slab (one b or one c), 16 tiles x 1024 elems.
// Tile t, half h (k 0..31 / 32..63), lane l=(g*16+n): elems
//   [t*1024 + h*512 + l*8 .. +8) = X[row = t*16 + n][k = h*32 + g*8 + j]
#define KFTILE 1024
#define KFSLAB (16 * KFTILE)   // 16384 elems = 32 KB per slab
#define BGRP   2               // b's per block in the scores kernel

typedef short short8 __attribute__((ext_vector_type(8)));   // 8 bf16 bit-patterns
typedef float f32x4 __attribute__((ext_vector_type(4)));

__device__ __forceinline__ unsigned short f32_to_bf16(float f) {
    unsigned int u = __float_as_uint(f);
    u += 0x7FFFu + ((u >> 16) & 1u);    // round to nearest even
    return (unsigned short)(u >> 16);
}

// fragment-major element offset for (row p, 16B-chunk cc)
__device__ __forceinline__ int frag_off(int p, int cc) {
    return ((p >> 4) * KFTILE) + ((cc >> 3) * 512) +
           (((((cc >> 1) & 3) * 16) + (p & 15)) * 8) + ((cc & 1) * 4);
}

// ---------------- prep: K AND Q compact/convert into fragment-major ----------------
__global__ __launch_bounds__(256)
void prep_kernel(const float* __restrict__ Q,
                 const float* __restrict__ K,
                 const int*   __restrict__ kmask,
                 const int*   __restrict__ qmask,
                 unsigned short* __restrict__ Qfrag,
                 unsigned short* __restrict__ Kfrag,
                 int* __restrict__ nvK,
                 int* __restrict__ nvQ) {
    const int tid  = threadIdx.x;
    const int lane = tid & 63;
    const int wave = tid >> 6;
    __shared__ int posArr[PL];
    __shared__ int wcnt[4];

    const bool isQ = (blockIdx.x >= 256);
    const int  bid = isQ ? (blockIdx.x - 256) : blockIdx.x;
    const int  idx     = bid >> 2;     // c or b
    const int  quarter = bid & 3;

    const int* mask = isQ ? (qmask + idx * PL) : (kmask + idx * PL);
    const int km = mask[tid];
    unsigned long long bal = __ballot(km != 0);
    int within = __popcll(bal & ((1ull << lane) - 1ull));
    if (lane == 0) wcnt[wave] = __popcll(bal);
    __syncthreads();
    int base = 0;
    #pragma unroll
    for (int w = 0; w < 4; ++w) base += (w < wave) ? wcnt[w] : 0;
    posArr[tid] = km ? (base + within) : -1;
    const int nv = wcnt[0] + wcnt[1] + wcnt[2] + wcnt[3];
    __syncthreads();

    const int sub = lane >> 4;     // row-within-group 0..3
    const int cl  = lane & 15;     // 16B column chunk
    const float* src = (isQ ? Q : K) + (size_t)idx * PL * PH;
    unsigned short* slab = (isQ ? Qfrag : Kfrag) + (size_t)idx * KFSLAB;

    #pragma unroll
    for (int it = 0; it < 4; ++it) {
        int r = quarter * 64 + it * 16 + wave * 4 + sub;
        int p = posArr[r];
        if (p >= 0) {
            float4 v = *(const float4*)(src + (size_t)r * PH + cl * 4);
            ushort4 o;
            o.x = f32_to_bf16(v.x); o.y = f32_to_bf16(v.y);
            o.z = f32_to_bf16(v.z); o.w = f32_to_bf16(v.w);
            *(ushort4*)(slab + frag_off(p, cl)) = o;
        }
    }

    if (!isQ) {
        const int rows16 = (nv + 15) & ~15;
        const int padChunks = (rows16 - nv) * 16;
        if (tid < padChunks) {
            int row = nv + (tid >> 4);
            if (row >= quarter * 64 && row < quarter * 64 + 64)
                *(ushort4*)(slab + frag_off(row, tid & 15)) = (ushort4){0, 0, 0, 0};
        }
        if (quarter == 0 && tid == 0) nvK[idx] = nv;
    } else {
        #pragma unroll
        for (int it = 0; it < 4; ++it) {
            int id2 = it * 256 + tid;
            int row = quarter * 64 + (id2 >> 4);
            if (row >= nv)
                *(ushort4*)(slab + frag_off(row, id2 & 15)) = (ushort4){0, 0, 0, 0};
        }
        if (quarter == 0 && tid == 0) nvQ[idx] = nv;
    }
}

// ---------------- main scores kernel: R8 structure + K-pair double-buffer ----------------
// The ct-loop's serial chain {4 K loads -> wait -> 16 MFMA} was 8 cold-latency
// exposures per wave (R11 probe: cold pass 30us vs warm 15.6us). Prefetch the
// NEXT ct-pair's 4 K fragments into named registers before computing the current
// pair: latency of pair ct+2 hides under 16 MFMAs of pair ct.
__global__ __launch_bounds__(256, 2)
void colbert_scores_mfma(const unsigned short* __restrict__ Qfrag,
                         const unsigned short* __restrict__ Kfrag,
                         const int*   __restrict__ nvK,
                         const int*   __restrict__ nvQ,
                         float*       __restrict__ scores) {
    const int c  = blockIdx.x;
    const int bg = blockIdx.y;
    const int tid  = threadIdx.x;
    const int wave = tid >> 6;
    const int lane = tid & 63;
    const int n    = lane & 15;        // col / row-within-tile index

    __shared__ float red[BGRP][4];

    const int nv       = nvK[c];
    const int ntFull   = nv >> 4;
    const int tailCols = nv & 15;

    const int b0  = bg * BGRP;
    const int nq0 = nvQ[b0];
    const int nq1 = nvQ[b0 + 1];
    const int ntQP = ((nq0 > nq1 ? nq0 : nq1) + 31) >> 5;   // q-tile-pairs (32 rows)

    const f32x4 ZERO4 = (f32x4){0.f, 0.f, 0.f, 0.f};
    const float biasv = (n < tailCols) ? 0.0f : NEG_INF_F;
    const f32x4 BIAS4 = (f32x4){biasv, biasv, biasv, biasv};

    const unsigned short* kb = Kfrag + (size_t)c * KFSLAB + lane * 8;

    float partial[BGRP] = {0.0f, 0.0f};

    for (int qp = wave; qp < ntQP; qp += 4) {
        // A-fragments for both b's, both q-tiles of the pair (one latency exposure)
        short8 aA[BGRP][2][2];
        #pragma unroll
        for (int bi = 0; bi < BGRP; ++bi) {
            const unsigned short* qbase = Qfrag + (size_t)(b0 + bi) * KFSLAB
                                         + qp * 2 * KFTILE + lane * 8;
            aA[bi][0][0] = *(const short8*)(qbase);
            aA[bi][0][1] = *(const short8*)(qbase + 512);
            aA[bi][1][0] = *(const short8*)(qbase + 1024);
            aA[bi][1][1] = *(const short8*)(qbase + 1536);
        }

        float maxv[BGRP][2][4];
        #pragma unroll
        for (int bi = 0; bi < BGRP; ++bi)
            #pragma unroll
            for (int t = 0; t < 2; ++t)
                #pragma unroll
                for (int r = 0; r < 4; ++r) maxv[bi][t][r] = NEG_INF_F;

        // ---- K-pair double-buffered main loop ----
        short8 kc0, kc1, kc2, kc3;     // current pair's fragments
        if (ntFull >= 2) {             // preload pair 0
            kc0 = *(const short8*)(kb);
            kc1 = *(const short8*)(kb + 512);
            kc2 = *(const short8*)(kb + 1024);
            kc3 = *(const short8*)(kb + 1536);
        }

        int ct = 0;
        for (; ct + 1 < ntFull; ct += 2) {
            // prefetch pair ct+2 (issued before the MFMA block below)
            short8 kp0, kp1, kp2, kp3;
            const bool more = (ct + 3 < ntFull);
            if (more) {
                const unsigned short* kn = kb + (ct + 2) * KFTILE;
                kp0 = *(const short8*)(kn);
                kp1 = *(const short8*)(kn + 512);
                kp2 = *(const short8*)(kn + 1024);
                kp3 = *(const short8*)(kn + 1536);
            }

            #pragma unroll
            for (int bi = 0; bi < BGRP; ++bi)
                #pragma unroll
                for (int t = 0; t < 2; ++t) {
                    f32x4 accA = __builtin_amdgcn_mfma_f32_16x16x32_bf16(aA[bi][t][0], kc0, ZERO4, 0, 0, 0);
                    accA = __builtin_amdgcn_mfma_f32_16x16x32_bf16(aA[bi][t][1], kc1, accA, 0, 0, 0);
                    f32x4 accB = __builtin_amdgcn_mfma_f32_16x16x32_bf16(aA[bi][t][0], kc2, ZERO4, 0, 0, 0);
                    accB = __builtin_amdgcn_mfma_f32_16x16x32_bf16(aA[bi][t][1], kc3, accB, 0, 0, 0);
                    #pragma unroll
                    for (int r = 0; r < 4; ++r)
                        maxv[bi][t][r] = fmaxf(maxv[bi][t][r], fmaxf(accA[r], accB[r]));
                }

            if (more) { kc0 = kp0; kc1 = kp1; kc2 = kp2; kc3 = kp3; }
        }

        // leftover single full tile
        if (ntFull & 1) {
            const unsigned short* ka = kb + ct * KFTILE;
            short8 k0 = *(const short8*)(ka);
            short8 k1 = *(const short8*)(ka + 512);
            #pragma unroll
            for (int bi = 0; bi < BGRP; ++bi)
                #pragma unroll
                for (int t = 0; t < 2; ++t) {
                    f32x4 acc = __builtin_amdgcn_mfma_f32_16x16x32_bf16(aA[bi][t][0], k0, ZERO4, 0, 0, 0);
                    acc = __builtin_amdgcn_mfma_f32_16x16x32_bf16(aA[bi][t][1], k1, acc, 0, 0, 0);
                    #pragma unroll
                    for (int r = 0; r < 4; ++r)
                        maxv[bi][t][r] = fmaxf(maxv[bi][t][r], acc[r]);
                }
            ct++;
        }

        // tail tile: pad lanes get NEG_INF via the MFMA C-operand bias
        if (tailCols) {
            const unsigned short* ka = kb + ct * KFTILE;
            short8 k0 = *(const short8*)(ka);
            short8 k1 = *(const short8*)(ka + 512);
            #pragma unroll
            for (int bi = 0; bi < BGRP; ++bi)
                #pragma unroll
                for (int t = 0; t < 2; ++t) {
                    f32x4 acc = __builtin_amdgcn_mfma_f32_16x16x32_bf16(aA[bi][t][0], k0, BIAS4, 0, 0, 0);
                    acc = __builtin_amdgcn_mfma_f32_16x16x32_bf16(aA[bi][t][1], k1, acc, 0, 0, 0);
                    #pragma unroll
                    for (int r = 0; r < 4; ++r)
                        maxv[bi][t][r] = fmaxf(maxv[bi][t][r], acc[r]);
                }
        }

        // col-reduce over the 16 lanes of each quad group; accumulate row sums
        #pragma unroll
        for (int bi = 0; bi < BGRP; ++bi)
            #pragma unroll
            for (int t = 0; t < 2; ++t)
                #pragma unroll
                for (int r = 0; r < 4; ++r) {
                    float mv = maxv[bi][t][r];
                    mv = fmaxf(mv, __shfl_xor(mv, 1, 16));
                    mv = fmaxf(mv, __shfl_xor(mv, 2, 16));
                    mv = fmaxf(mv, __shfl_xor(mv, 4, 16));
                    mv = fmaxf(mv, __shfl_xor(mv, 8, 16));
                    if (n == 0) partial[bi] += mv;   // each (g,t,r) = one distinct q row
                }
    }

    #pragma unroll
    for (int bi = 0; bi < BGRP; ++bi) {
        float p = partial[bi];
        p += __shfl_xor(p, 16, 64);
        p += __shfl_xor(p, 32, 64);
        if (lane == 0) red[bi][wave] = p;
    }

    __syncthreads();
    if (tid < BGRP) {
        float total = red[tid][0] + red[tid][1] + red[tid][2] + red[tid][3];
        scores[(b0 + tid) * PB + c] = total * (1.0f / TEMP);
    }
}

// ---------------- finalize: log-softmax CE ----------------
__global__ void finalize_kernel(const float* __restrict__ scores,
                                const int*   __restrict__ labels,
                                float*       __restrict__ out) {
    const int r = threadIdx.x;   // 64 threads, one per row
    const float* row = scores + r * PB;
    float mx = NEG_INF_F;
    for (int j = 0; j < PB; ++j) mx = fmaxf(mx, row[j]);
    float se = 0.0f;
    for (int j = 0; j < PB; ++j) se += expf(row[j] - mx);
    float logp_diag = row[r] - mx - logf(se);
    float w = (float)labels[r];
    float wd = w * logp_diag;
    #pragma unroll
    for (int off = 32; off >= 1; off >>= 1) {
        wd += __shfl_xor(wd, off, 64);
        w  += __shfl_xor(w,  off, 64);
    }
    if (r == 0) out[0] = -wd / fmaxf(w, 1.0f);
}

extern "C" void kernel_launch(void* const* d_in, const int* in_sizes, int n_in,
                              void* d_out, int out_size, void* d_ws, size_t ws_size,
                              hipStream_t stream) {
    const float* Q      = (const float*)d_in[0];
    const float* K      = (const float*)d_in[1];
    const int*   labels = (const int*)d_in[2];
    const int*   qmask  = (const int*)d_in[3];
    const int*   kmask  = (const int*)d_in[4];
    float*       out    = (float*)d_out;

    // ws layout: [scores 16KB][Qfrag 2MB][Kfrag 2MB][nvK 256B][nvQ 256B]
    char* ws = (char*)d_ws;
    float*          scores = (float*)ws;
    unsigned short* Qfrag  = (unsigned short*)(ws + 16 * 1024);
    unsigned short* Kfrag  = (unsigned short*)(ws + 16 * 1024 + 2 * 1024 * 1024);
    int*            nvK    = (int*)(ws + 16 * 1024 + 4 * 1024 * 1024);
    int*            nvQ    = nvK + 64;

    prep_kernel<<<512, 256, 0, stream>>>(Q, K, kmask, qmask, Qfrag, Kfrag, nvK, nvQ);

    dim3 grid(PB, PB / BGRP);
    colbert_scores_mfma<<<grid, 256, 0, stream>>>(Qfrag, Kfrag, nvK, nvQ, scores);
    finalize_kernel<<<1, 64, 0, stream>>>(scores, labels, out);
}

// Round 14
// 93.534 us; speedup vs baseline: 1.5121x; 1.0433x over previous
//
#include <hip/hip_runtime.h>
#include <math.h>

// Problem constants: B=64, L=256, H=64
#define PB 64
#define PL 256
#define PH 64
#define TEMP 0.07f
#define NEG_INF_F (-1e9f)

// Fragment-major layout: per slab (one b or one c), 16 tiles x 1024 elems.
// Tile t, half h (k 0..31 / 32..63), lane l=(g*16+n): elems
//   [t*1024 + h*512 + l*8 .. +8) = X[row = t*16 + n][k = h*32 + g*8 + j]
// -> every 64-lane fragment load is one fully-coalesced 1KB dwordx4 read.
#define KFTILE 1024
#define KFSLAB (16 * KFTILE)   // 16384 elems = 32 KB per slab
#define BGRP   2               // b's per block in the scores kernel

typedef short short8 __attribute__((ext_vector_type(8)));   // 8 bf16 bit-patterns
typedef float f32x4 __attribute__((ext_vector_type(4)));

__device__ __forceinline__ unsigned short f32_to_bf16(float f) {
    unsigned int u = __float_as_uint(f);
    u += 0x7FFFu + ((u >> 16) & 1u);    // round to nearest even
    return (unsigned short)(u >> 16);
}

// fragment-major element offset for (row p, 16B-chunk cc) ; cc covers k=cc*4..cc*4+3
__device__ __forceinline__ int frag_off(int p, int cc) {
    return ((p >> 4) * KFTILE) + ((cc >> 3) * 512) +
           (((((cc >> 1) & 3) * 16) + (p & 15)) * 8) + ((cc & 1) * 4);
}

// ---------------- prep: K AND Q compact/convert into fragment-major ----------------
// blocks 0..255   : K compaction. c = bid>>2, quarter = bid&3. Tail zero rows to x16.
// blocks 256..511 : Q compaction. b = (bid-256)>>2. ALL rows >= nvQ zero-filled.
__global__ __launch_bounds__(256)
void prep_kernel(const float* __restrict__ Q,
                 const float* __restrict__ K,
                 const int*   __restrict__ kmask,
                 const int*   __restrict__ qmask,
                 unsigned short* __restrict__ Qfrag,
                 unsigned short* __restrict__ Kfrag,
                 int* __restrict__ nvK,
                 int* __restrict__ nvQ) {
    const int tid  = threadIdx.x;
    const int lane = tid & 63;
    const int wave = tid >> 6;
    __shared__ int posArr[PL];
    __shared__ int wcnt[4];

    const bool isQ = (blockIdx.x >= 256);
    const int  bid = isQ ? (blockIdx.x - 256) : blockIdx.x;
    const int  idx     = bid >> 2;     // c or b
    const int  quarter = bid & 3;

    const int* mask = isQ ? (qmask + idx * PL) : (kmask + idx * PL);
    const int km = mask[tid];
    unsigned long long bal = __ballot(km != 0);
    int within = __popcll(bal & ((1ull << lane) - 1ull));
    if (lane == 0) wcnt[wave] = __popcll(bal);
    __syncthreads();
    int base = 0;
    #pragma unroll
    for (int w = 0; w < 4; ++w) base += (w < wave) ? wcnt[w] : 0;
    posArr[tid] = km ? (base + within) : -1;
    const int nv = wcnt[0] + wcnt[1] + wcnt[2] + wcnt[3];
    __syncthreads();

    const int sub = lane >> 4;     // row-within-group 0..3
    const int cl  = lane & 15;     // 16B column chunk (k = cl*4..cl*4+3)
    const float* src = (isQ ? Q : K) + (size_t)idx * PL * PH;
    unsigned short* slab = (isQ ? Qfrag : Kfrag) + (size_t)idx * KFSLAB;

    // copy 64 rows: 4 waves x 4 rows/iter x 4 iters; 16 lanes per row (coalesced reads)
    #pragma unroll
    for (int it = 0; it < 4; ++it) {
        int r = quarter * 64 + it * 16 + wave * 4 + sub;
        int p = posArr[r];
        if (p >= 0) {
            float4 v = *(const float4*)(src + (size_t)r * PH + cl * 4);
            ushort4 o;
            o.x = f32_to_bf16(v.x); o.y = f32_to_bf16(v.y);
            o.z = f32_to_bf16(v.z); o.w = f32_to_bf16(v.w);
            *(ushort4*)(slab + frag_off(p, cl)) = o;
        }
    }

    if (!isQ) {
        // zero tail pad rows up to multiple of 16 (<=240 chunks, single shot)
        const int rows16 = (nv + 15) & ~15;
        const int padChunks = (rows16 - nv) * 16;
        if (tid < padChunks) {
            int row = nv + (tid >> 4);
            if (row >= quarter * 64 && row < quarter * 64 + 64)
                *(ushort4*)(slab + frag_off(row, tid & 15)) = (ushort4){0, 0, 0, 0};
        }
        if (quarter == 0 && tid == 0) nvK[idx] = nv;
    } else {
        // zero-fill ALL rows >= nv inside this quarter's window (1024 chunks / 4 iters)
        #pragma unroll
        for (int it = 0; it < 4; ++it) {
            int id2 = it * 256 + tid;            // (row-in-quarter, chunk)
            int row = quarter * 64 + (id2 >> 4);
            if (row >= nv)
                *(ushort4*)(slab + frag_off(row, id2 & 15)) = (ushort4){0, 0, 0, 0};
        }
        if (quarter == 0 && tid == 0) nvQ[idx] = nv;
    }
}

// ---------------- main scores kernel: one block per (c, b-pair) ----------------
// No LDS staging: K/Q fragments read directly from L2-hot fragment-major buffers
// (2MB each) with coalesced dwordx4 loads. No barriers in the compute path.
__global__ __launch_bounds__(256, 2)
void colbert_scores_mfma(const unsigned short* __restrict__ Qfrag,
                         const unsigned short* __restrict__ Kfrag,
                         const int*   __restrict__ nvK,
                         const int*   __restrict__ nvQ,
                         float*       __restrict__ scores) {
    const int c  = blockIdx.x;
    const int bg = blockIdx.y;
    const int tid  = threadIdx.x;
    const int wave = tid >> 6;
    const int lane = tid & 63;
    const int n    = lane & 15;        // col / row-within-tile index

    __shared__ float red[BGRP][4];

    const int nv       = nvK[c];
    const int ntFull   = nv >> 4;
    const int tailCols = nv & 15;

    const int b0  = bg * BGRP;
    const int nq0 = nvQ[b0];
    const int nq1 = nvQ[b0 + 1];
    const int ntQP = ((nq0 > nq1 ? nq0 : nq1) + 31) >> 5;   // q-tile-pairs (32 rows)

    const f32x4 ZERO4 = (f32x4){0.f, 0.f, 0.f, 0.f};
    const float biasv = (n < tailCols) ? 0.0f : NEG_INF_F;
    const f32x4 BIAS4 = (f32x4){biasv, biasv, biasv, biasv};

    const unsigned short* kb = Kfrag + (size_t)c * KFSLAB + lane * 8;

    float partial[BGRP] = {0.0f, 0.0f};

    for (int qp = wave; qp < ntQP; qp += 4) {
        // A-fragments for both b's, both q-tiles of the pair (coalesced 1KB loads)
        short8 aA[BGRP][2][2];
        #pragma unroll
        for (int bi = 0; bi < BGRP; ++bi) {
            const unsigned short* qbase = Qfrag + (size_t)(b0 + bi) * KFSLAB
                                         + qp * 2 * KFTILE + lane * 8;
            aA[bi][0][0] = *(const short8*)(qbase);
            aA[bi][0][1] = *(const short8*)(qbase + 512);
            aA[bi][1][0] = *(const short8*)(qbase + 1024);
            aA[bi][1][1] = *(const short8*)(qbase + 1536);
        }

        float maxv[BGRP][2][4];
        #pragma unroll
        for (int bi = 0; bi < BGRP; ++bi)
            #pragma unroll
            for (int t = 0; t < 2; ++t)
                #pragma unroll
                for (int r = 0; r < 4; ++r) maxv[bi][t][r] = NEG_INF_F;

        int ct = 0;
        for (; ct + 1 < ntFull; ct += 2) {
            const unsigned short* ka = kb + ct * KFTILE;
            short8 kA0 = *(const short8*)(ka);
            short8 kA1 = *(const short8*)(ka + 512);
            short8 kB0 = *(const short8*)(ka + 1024);
            short8 kB1 = *(const short8*)(ka + 1536);

            #pragma unroll
            for (int bi = 0; bi < BGRP; ++bi)
                #pragma unroll
                for (int t = 0; t < 2; ++t) {
                    f32x4 accA = __builtin_amdgcn_mfma_f32_16x16x32_bf16(aA[bi][t][0], kA0, ZERO4, 0, 0, 0);
                    accA = __builtin_amdgcn_mfma_f32_16x16x32_bf16(aA[bi][t][1], kA1, accA, 0, 0, 0);
                    f32x4 accB = __builtin_amdgcn_mfma_f32_16x16x32_bf16(aA[bi][t][0], kB0, ZERO4, 0, 0, 0);
                    accB = __builtin_amdgcn_mfma_f32_16x16x32_bf16(aA[bi][t][1], kB1, accB, 0, 0, 0);
                    #pragma unroll
                    for (int r = 0; r < 4; ++r)
                        maxv[bi][t][r] = fmaxf(maxv[bi][t][r], fmaxf(accA[r], accB[r]));
                }
        }

        if (ntFull & 1) {
            const unsigned short* ka = kb + ct * KFTILE;
            short8 k0 = *(const short8*)(ka);
            short8 k1 = *(const short8*)(ka + 512);
            #pragma unroll
            for (int bi = 0; bi < BGRP; ++bi)
                #pragma unroll
                for (int t = 0; t < 2; ++t) {
                    f32x4 acc = __builtin_amdgcn_mfma_f32_16x16x32_bf16(aA[bi][t][0], k0, ZERO4, 0, 0, 0);
                    acc = __builtin_amdgcn_mfma_f32_16x16x32_bf16(aA[bi][t][1], k1, acc, 0, 0, 0);
                    #pragma unroll
                    for (int r = 0; r < 4; ++r)
                        maxv[bi][t][r] = fmaxf(maxv[bi][t][r], acc[r]);
                }
            ct++;
        }

        if (tailCols) {
            const unsigned short* ka = kb + ct * KFTILE;
            short8 k0 = *(const short8*)(ka);
            short8 k1 = *(const short8*)(ka + 512);
            #pragma unroll
            for (int bi = 0; bi < BGRP; ++bi)
                #pragma unroll
                for (int t = 0; t < 2; ++t) {
                    f32x4 acc = __builtin_amdgcn_mfma_f32_16x16x32_bf16(aA[bi][t][0], k0, BIAS4, 0, 0, 0);
                    acc = __builtin_amdgcn_mfma_f32_16x16x32_bf16(aA[bi][t][1], k1, acc, 0, 0, 0);
                    #pragma unroll
                    for (int r = 0; r < 4; ++r)
                        maxv[bi][t][r] = fmaxf(maxv[bi][t][r], acc[r]);
                }
        }

        // col-reduce over the 16 lanes of each quad group; accumulate row sums
        #pragma unroll
        for (int bi = 0; bi < BGRP; ++bi)
            #pragma unroll
            for (int t = 0; t < 2; ++t)
                #pragma unroll
                for (int r = 0; r < 4; ++r) {
                    float mv = maxv[bi][t][r];
                    mv = fmaxf(mv, __shfl_xor(mv, 1, 16));
                    mv = fmaxf(mv, __shfl_xor(mv, 2, 16));
                    mv = fmaxf(mv, __shfl_xor(mv, 4, 16));
                    mv = fmaxf(mv, __shfl_xor(mv, 8, 16));
                    if (n == 0) partial[bi] += mv;   // each (g,t,r) = one distinct q row
                }
    }

    #pragma unroll
    for (int bi = 0; bi < BGRP; ++bi) {
        float p = partial[bi];
        p += __shfl_xor(p, 16, 64);
        p += __shfl_xor(p, 32, 64);
        if (lane == 0) red[bi][wave] = p;
    }

    __syncthreads();
    if (tid < BGRP) {
        float total = red[tid][0] + red[tid][1] + red[tid][2] + red[tid][3];
        scores[(b0 + tid) * PB + c] = total * (1.0f / TEMP);
    }
}

// ---------------- finalize: log-softmax CE ----------------
__global__ void finalize_kernel(const float* __restrict__ scores,
                                const int*   __restrict__ labels,
                                float*       __restrict__ out) {
    const int r = threadIdx.x;   // 64 threads, one per row
    const float* row = scores + r * PB;
    float mx = NEG_INF_F;
    for (int j = 0; j < PB; ++j) mx = fmaxf(mx, row[j]);
    float se = 0.0f;
    for (int j = 0; j < PB; ++j) se += expf(row[j] - mx);
    float logp_diag = row[r] - mx - logf(se);
    float w = (float)labels[r];
    float wd = w * logp_diag;
    #pragma unroll
    for (int off = 32; off >= 1; off >>= 1) {
        wd += __shfl_xor(wd, off, 64);
        w  += __shfl_xor(w,  off, 64);
    }
    if (r == 0) out[0] = -wd / fmaxf(w, 1.0f);
}

extern "C" void kernel_launch(void* const* d_in, const int* in_sizes, int n_in,
                              void* d_out, int out_size, void* d_ws, size_t ws_size,
                              hipStream_t stream) {
    const float* Q      = (const float*)d_in[0];
    const float* K      = (const float*)d_in[1];
    const int*   labels = (const int*)d_in[2];
    const int*   qmask  = (const int*)d_in[3];
    const int*   kmask  = (const int*)d_in[4];
    float*       out    = (float*)d_out;

    // ws layout: [scores 16KB][Qfrag 2MB][Kfrag 2MB][nvK 256B][nvQ 256B]
    char* ws = (char*)d_ws;
    float*          scores = (float*)ws;
    unsigned short* Qfrag  = (unsigned short*)(ws + 16 * 1024);
    unsigned short* Kfrag  = (unsigned short*)(ws + 16 * 1024 + 2 * 1024 * 1024);
    int*            nvK    = (int*)(ws + 16 * 1024 + 4 * 1024 * 1024);
    int*            nvQ    = nvK + 64;

    prep_kernel<<<512, 256, 0, stream>>>(Q, K, kmask, qmask, Qfrag, Kfrag, nvK, nvQ);

    dim3 grid(PB, PB / BGRP);
    colbert_scores_mfma<<<grid, 256, 0, stream>>>(Qfrag, Kfrag, nvK, nvQ, scores);
    finalize_kernel<<<1, 64, 0, stream>>>(scores, labels, out);
}